// Round 22
// baseline (103.648 us; speedup 1.0000x reference)
//
#include <hip/hip_runtime.h>

#define HID 64
#define IN_DIM 128
// binC (float values)
#define RANGE_BITS 14
#define RANGE (1 << RANGE_BITS)   // 16384 nodes per 64 KB float bucket
#define NB 7
#define MCH 36
#define SCAN_TPB 512
// binA (packed u16 counters)
#define RB2 15
#define RANGE2 (1 << RB2)         // 32768 nodes per 64 KB u16 bucket
#define NB2 4
#define MCH2 64
// dense staging
#define DNODES 64                 // nodes per dense block
#define SK 32                     // floats per chunk-row (one full 128B line)
#define NCH (IN_DIM / SK)         // 4 chunks

// ---------------- dense: whole x-tile staged once, ONE barrier, then pure FMA ----------------
// Wave w: channel quarter q=w (SGPR via readfirstlane -> W scalar path), lane = node.
// All 4 chunks (32 KB) staged up front from 8 in-flight float4 loads/thread; a single
// __syncthreads; then 128 k-steps of FMA with pipelined swizzled ds_read_b128 (no more
// barriers, no vmcnt waits inside the loop).
__global__ __launch_bounds__(256) void k_dense(const float* __restrict__ x,
                                               const float* __restrict__ W_in,
                                               const float* __restrict__ b_in,
                                               const float* __restrict__ W_g,
                                               const float* __restrict__ W_out,
                                               float* __restrict__ zpart,
                                               int N, int Npad) {
    __shared__ float weff_l[HID];
    __shared__ float xt[NCH * DNODES * SK];   // 32 KB: chunk-major [c][row][32]

    const int t = threadIdx.x;
    const int row0 = blockIdx.x * DNODES;

    // ---- issue all x loads first: 8 float4/thread, all in flight ----
    float4 rg[8];
    const int lrow  = t >> 3;              // 0..31
    const int lslot = t & 7;               // 16B slot in the 128B chunk-row
    {
        int gr0 = row0 + lrow;        if (gr0 >= N) gr0 = N - 1;
        int gr1 = row0 + 32 + lrow;   if (gr1 >= N) gr1 = N - 1;
        const float* p0 = x + (size_t)gr0 * IN_DIM + lslot * 4;
        const float* p1 = x + (size_t)gr1 * IN_DIM + lslot * 4;
#pragma unroll
        for (int c = 0; c < NCH; ++c) {
            rg[c * 2 + 0] = *(const float4*)(p0 + c * SK);
            rg[c * 2 + 1] = *(const float4*)(p1 + c * SK);
        }
    }

    // ---- weff = W_g @ W_out, lane-parallel (overlaps x-load latency) ----
    {
        const float* wg = W_g + (t >> 2) * HID + (t & 3) * 16;
        const float* wo = W_out + (t & 3) * 16;
        float s = 0.0f;
#pragma unroll
        for (int p = 0; p < 16; ++p) s = fmaf(wg[p], wo[p], s);
        s += __shfl_xor(s, 1, 64);
        s += __shfl_xor(s, 2, 64);
        if ((t & 3) == 0) weff_l[t >> 2] = s;
    }

    // ---- write the whole tile (swizzled 16B slots), one barrier ----
    const int woff = (lslot ^ (lrow & 7)) << 2;   // row parity = lrow&7 for both segs
#pragma unroll
    for (int c = 0; c < NCH; ++c) {
        *(float4*)&xt[(c * DNODES + lrow)      * SK + woff] = rg[c * 2 + 0];
        *(float4*)&xt[(c * DNODES + 32 + lrow) * SK + woff] = rg[c * 2 + 1];
    }
    __syncthreads();

    const int q = __builtin_amdgcn_readfirstlane(t >> 6);  // channel quarter (SGPR)
    const int nidx = t & 63;
    int node = row0 + nidx;
    if (node >= N) node = N - 1;

    float acc[16];
#pragma unroll
    for (int jj = 0; jj < 16; ++jj)
        acc[jj] = b_in[q * 16 + jj];       // uniform -> s_load

    const int rkey = nidx & 7;
#pragma unroll
    for (int c = 0; c < NCH; ++c) {
        const float* xrow = &xt[(c * DNODES + nidx) * SK];
#pragma unroll
        for (int k4 = 0; k4 < SK / 4; ++k4) {
            float4 xq = *(const float4*)&xrow[(k4 ^ rkey) << 2];  // ds_read_b128
            const float xk[4] = {xq.x, xq.y, xq.z, xq.w};
#pragma unroll
            for (int kk = 0; kk < 4; ++kk) {
                const float* wr = W_in + (c * SK + k4 * 4 + kk) * HID + q * 16;  // uniform
#pragma unroll
                for (int jj = 0; jj < 16; ++jj)
                    acc[jj] = fmaf(xk[kk], wr[jj], acc[jj]);
            }
        }
    }

    float zv = 0.0f;
#pragma unroll
    for (int jj = 0; jj < 16; ++jj)
        zv = fmaf(fmaxf(acc[jj], 0.0f), weff_l[q * 16 + jj], zv);
    zpart[(size_t)q * Npad + node] = zv;
}

// ---------------- pass A: binned degree count, packed u16 (LDS atomics only) ----------------
__global__ __launch_bounds__(SCAN_TPB) void k_binA(const int* __restrict__ dst,
                                                   unsigned* __restrict__ partA,
                                                   int E, int chunkA) {
    __shared__ unsigned cnt[RANGE2 / 2];   // 64 KB, 2 nodes per word
    for (int i = threadIdx.x; i < RANGE2 / 2; i += SCAN_TPB) cnt[i] = 0;
    __syncthreads();

    const int r = blockIdx.x % NB2;
    const int lo = r << RB2;
    const int e0 = (blockIdx.x / NB2) * chunkA;
    const int e1 = min(E, e0 + chunkA);
    for (int e = e0 + (int)threadIdx.x * 4; e + 3 < e1; e += SCAN_TPB * 4) {
        int4 d4 = *(const int4*)(dst + e);
        unsigned v;
        v = (unsigned)(d4.x - lo); if (v < RANGE2) atomicAdd(&cnt[v >> 1], 1u << ((v & 1) << 4));
        v = (unsigned)(d4.y - lo); if (v < RANGE2) atomicAdd(&cnt[v >> 1], 1u << ((v & 1) << 4));
        v = (unsigned)(d4.z - lo); if (v < RANGE2) atomicAdd(&cnt[v >> 1], 1u << ((v & 1) << 4));
        v = (unsigned)(d4.w - lo); if (v < RANGE2) atomicAdd(&cnt[v >> 1], 1u << ((v & 1) << 4));
    }
    __syncthreads();

    unsigned* outp = partA + (size_t)blockIdx.x * (RANGE2 / 2);
    for (int i = threadIdx.x; i < RANGE2 / 2; i += SCAN_TPB) outp[i] = cnt[i];
}

// ------- reduce deg (unpack u16) -> dinv, zs = (zpart0+..+zpart3) * dinv -------
__global__ __launch_bounds__(256) void k_redDeg(const unsigned* __restrict__ partA,
                                                const float* __restrict__ zpart,
                                                float* __restrict__ dinv,
                                                float* __restrict__ zs,
                                                int N, int Npad) {
    int i = blockIdx.x * blockDim.x + threadIdx.x;
    if (i >= N) return;
    const int r = i >> RB2, idx = i & (RANGE2 - 1);
    const int sh = (idx & 1) << 4;
    int d = 0;
#pragma unroll 4
    for (int m = 0; m < MCH2; ++m) {
        unsigned w = partA[((size_t)m * NB2 + r) * (RANGE2 / 2) + (idx >> 1)];
        d += (int)((w >> sh) & 0xFFFFu);
    }
    float di = rsqrtf((float)d + 1.0f);
    dinv[i] = di;
    float z = zpart[i] + zpart[(size_t)Npad + i]
            + zpart[2 * (size_t)Npad + i] + zpart[3 * (size_t)Npad + i];
    zs[i] = z * di;
}

// ---------------- pass C: binned value scatter (LDS float atomics only) ----------------
__global__ __launch_bounds__(SCAN_TPB) void k_binC(const int* __restrict__ eidx,
                                                   const float* __restrict__ zs,
                                                   float* __restrict__ partf,
                                                   int E, int chunk) {
    __shared__ float acc[RANGE];
    for (int i = threadIdx.x; i < RANGE; i += SCAN_TPB) acc[i] = 0.0f;
    __syncthreads();

    const int r = blockIdx.x % NB;
    const int lo = r << RANGE_BITS;
    const int e0 = (blockIdx.x / NB) * chunk;
    const int e1 = min(E, e0 + chunk);
    for (int e = e0 + (int)threadIdx.x * 4; e + 3 < e1; e += SCAN_TPB * 4) {
        int4 s4 = *(const int4*)(eidx + e);        // src
        int4 d4 = *(const int4*)(eidx + E + e);    // dst
        unsigned v;
        v = (unsigned)(d4.x - lo); if (v < RANGE) atomicAdd(&acc[v], zs[s4.x]);
        v = (unsigned)(d4.y - lo); if (v < RANGE) atomicAdd(&acc[v], zs[s4.y]);
        v = (unsigned)(d4.z - lo); if (v < RANGE) atomicAdd(&acc[v], zs[s4.z]);
        v = (unsigned)(d4.w - lo); if (v < RANGE) atomicAdd(&acc[v], zs[s4.w]);
    }
    __syncthreads();

    float* outp = partf + (size_t)blockIdx.x * RANGE;
    for (int i = threadIdx.x; i < RANGE; i += SCAN_TPB) outp[i] = acc[i];
}

// ------- final: out = dinv * (sum partials + zs[self]) + (b_g.W_out + b_out) -------
__global__ __launch_bounds__(256) void k_redFinal(const float* __restrict__ partf,
                                                  const float* __restrict__ dinv,
                                                  const float* __restrict__ zs,
                                                  const float* __restrict__ b_g,
                                                  const float* __restrict__ W_out,
                                                  const float* __restrict__ b_out,
                                                  float* __restrict__ out, int N) {
    const int lane = threadIdx.x & 63;
    float c = b_g[lane] * W_out[lane];
#pragma unroll
    for (int off = 32; off > 0; off >>= 1)
        c += __shfl_xor(c, off, 64);
    c += b_out[0];

    int i = blockIdx.x * blockDim.x + threadIdx.x;
    if (i >= N) return;
    const int r = i >> RANGE_BITS, idx = i & (RANGE - 1);
    float a = zs[i];   // self-loop
#pragma unroll 4
    for (int m = 0; m < MCH; ++m)
        a += partf[((size_t)m * NB + r) * RANGE + idx];
    out[i] = fmaf(dinv[i], a, c);
}

// ---------------- launch ----------------

extern "C" void kernel_launch(void* const* d_in, const int* in_sizes, int n_in,
                              void* d_out, int out_size, void* d_ws, size_t ws_size,
                              hipStream_t stream) {
    const float* x     = (const float*)d_in[0];
    const int*   eidx  = (const int*)d_in[1];
    const float* W_in  = (const float*)d_in[2];
    const float* b_in  = (const float*)d_in[3];
    const float* W_g   = (const float*)d_in[4];
    const float* b_g   = (const float*)d_in[5];
    const float* W_out = (const float*)d_in[6];
    const float* b_out = (const float*)d_in[7];
    float* out = (float*)d_out;

    const int N = in_sizes[0] / IN_DIM;   // 100000
    const int E = in_sizes[1] / 2;        // 1600000

    // chunks: multiples of 4
    const int chunk  = (((E + MCH  - 1) / MCH ) + 3) & ~3;
    const int chunkA = (((E + MCH2 - 1) / MCH2) + 3) & ~3;

    // ws layout: region0 = max(partf 16.5MB, partA 16.8MB) | zpart[4*Npad] | dinv[N] | zs[N]
    const size_t partElems0 = (size_t)NB * MCH * RANGE;              // binC floats
    const size_t partElemsA = (size_t)NB2 * MCH2 * (RANGE2 / 2);     // binA u32 words
    const size_t partElems = partElems0 > partElemsA ? partElems0 : partElemsA;
    const int Npad = (N + 63) & ~63;
    unsigned* partA = (unsigned*)d_ws;    // consumed by redDeg before binC overwrites
    float*    partf = (float*)d_ws;
    float*    zpart = (float*)d_ws + partElems;
    float*    dinv  = zpart + 4 * (size_t)Npad;
    float*    zs    = dinv + N;

    const int nG = (N + DNODES - 1) / DNODES;   // 1563 dense blocks
    k_binA<<<NB2 * MCH2, SCAN_TPB, 0, stream>>>(eidx + E, partA, E, chunkA);
    k_dense<<<nG, 256, 0, stream>>>(x, W_in, b_in, W_g, W_out, zpart, N, Npad);
    k_redDeg<<<(N + 255) / 256, 256, 0, stream>>>(partA, zpart, dinv, zs, N, Npad);
    k_binC<<<NB * MCH, SCAN_TPB, 0, stream>>>(eidx, zs, partf, E, chunk);
    k_redFinal<<<(N + 255) / 256, 256, 0, stream>>>(partf, dinv, zs, b_g, W_out, b_out, out, N);
}

// Round 23
// 80.384 us; speedup vs baseline: 1.2894x; 1.2894x over previous
//
#include <hip/hip_runtime.h>

#define HID 64
#define IN_DIM 128
// binC (float values)
#define RANGE_BITS 14
#define RANGE (1 << RANGE_BITS)   // 16384 nodes per 64 KB float bucket
#define NB 7
#define MCH 36
#define SCAN_TPB 512
// binA (packed u16 counters)
#define RB2 15
#define RANGE2 (1 << RB2)         // 32768 nodes per 64 KB u16 bucket
#define NB2 4
#define MCH2 64
// dense staging
#define DNODES 64                 // nodes per dense block
#define SK 32                     // floats of each row per chunk (one full 128B line)
#define NCH (IN_DIM / SK)         // 4 chunks
#define LDSP (DNODES + 1)         // 65: write banks 4a+b all-distinct, reads 2-way (free)

// ---- dense + fused deg-reduce: 64-node blocks, 4 channel-quarters, r20 tile ----
// Wave w: channel quarter q=w (SGPR via readfirstlane -> W scalar path), lane = node.
// x chunk staged once per block (8.3 KB LDS transposed [SK][65]); after FMA, block
// exchanges quarter-partials in LDS and wave 0 computes deg (from binA u16 partials),
// dinv = rsqrt(deg+1), zs = z*dinv — k_redDeg eliminated.
__global__ __launch_bounds__(256) void k_dense(const float* __restrict__ x,
                                               const float* __restrict__ W_in,
                                               const float* __restrict__ b_in,
                                               const float* __restrict__ W_g,
                                               const float* __restrict__ W_out,
                                               const unsigned* __restrict__ partA,
                                               float* __restrict__ dinv,
                                               float* __restrict__ zs,
                                               int N) {
    __shared__ float weff_l[HID];
    __shared__ float ldsT[SK][LDSP];       // 8.3 KB
    __shared__ float zp[4][DNODES];        // quarter partials (1 KB)

    const int t = threadIdx.x;

    // lane-parallel w_eff = W_g @ W_out: thread t -> j = t>>2, jp block = (t&3)*16
    {
        const float* wg = W_g + (t >> 2) * HID + (t & 3) * 16;   // coalesced 64B/4lanes
        const float* wo = W_out + (t & 3) * 16;
        float s = 0.0f;
#pragma unroll
        for (int p = 0; p < 16; ++p) s = fmaf(wg[p], wo[p], s);
        s += __shfl_xor(s, 1, 64);
        s += __shfl_xor(s, 2, 64);
        if ((t & 3) == 0) weff_l[t >> 2] = s;
    }

    const int q = __builtin_amdgcn_readfirstlane(t >> 6);  // channel quarter 0..3 (SGPR)
    const int nidx = t & 63;               // node within block
    const int row0 = blockIdx.x * DNODES;
    int node = row0 + nidx;
    if (node >= N) node = N - 1;           // clamped threads duplicate-write identical values

    float acc[16];
#pragma unroll
    for (int jj = 0; jj < 16; ++jj)
        acc[jj] = b_in[q * 16 + jj];       // uniform -> s_load

    // staging: 2 float4/thread/chunk. seg s: row = s*32 + (t>>3), col = (t&7)*4.
    float4 rg[2];
    const int lrow = t >> 3;               // 0..31
    const int lcol = (t & 7) * 4;          // 0,4,...,28

#define LOADC(c)                                                                 \
    {                                                                            \
        _Pragma("unroll")                                                        \
        for (int s = 0; s < 2; ++s) {                                            \
            int grow = row0 + s * 32 + lrow;                                     \
            if (grow >= N) grow = N - 1;                                         \
            rg[s] = *(const float4*)(x + (size_t)grow * IN_DIM + (c) * SK + lcol); \
        }                                                                        \
    }
#define WRITEC()                                                                 \
    {                                                                            \
        _Pragma("unroll")                                                        \
        for (int s = 0; s < 2; ++s) {                                            \
            ldsT[lcol + 0][s * 32 + lrow] = rg[s].x;                             \
            ldsT[lcol + 1][s * 32 + lrow] = rg[s].y;                             \
            ldsT[lcol + 2][s * 32 + lrow] = rg[s].z;                             \
            ldsT[lcol + 3][s * 32 + lrow] = rg[s].w;                             \
        }                                                                        \
    }

    LOADC(0);
    for (int c = 0; c < NCH; ++c) {
        WRITEC();                          // LDS <- rg (chunk c)
        __syncthreads();                   // writes visible (also covers weff_l)
        if (c + 1 < NCH) LOADC(c + 1);     // global->reg, overlaps compute
#pragma unroll 8
        for (int kk = 0; kk < SK; ++kk) {
            float xv = ldsT[kk][nidx];     // (kk+nidx)%32 banks: 2-way, free
            const float* wr = W_in + (c * SK + kk) * HID + q * 16;  // uniform -> s_load
#pragma unroll
            for (int jj = 0; jj < 16; ++jj)
                acc[jj] = fmaf(xv, wr[jj], acc[jj]);
        }
        __syncthreads();                   // reads done before next WRITEC
    }
#undef LOADC
#undef WRITEC

    float zv = 0.0f;
#pragma unroll
    for (int jj = 0; jj < 16; ++jj)
        zv = fmaf(fmaxf(acc[jj], 0.0f), weff_l[q * 16 + jj], zv);
    zp[q][nidx] = zv;
    __syncthreads();

    // ---- fused redDeg: wave 0 sums quarters + unpacks deg partials ----
    if (t < 64) {
        float z = zp[0][t] + zp[1][t] + zp[2][t] + zp[3][t];
        const int n = node;                // == row0 + t (clamped)
        const int r = n >> RB2, idx = n & (RANGE2 - 1);
        const int sh = (idx & 1) << 4;
        const unsigned* base = partA + (size_t)r * (RANGE2 / 2) + (idx >> 1);
        const size_t stride = (size_t)NB2 * (RANGE2 / 2);
        int d = 0;
#pragma unroll 8
        for (int m = 0; m < MCH2; ++m)
            d += (int)((base[m * stride] >> sh) & 0xFFFFu);
        float di = rsqrtf((float)d + 1.0f);
        dinv[n] = di;
        zs[n]   = z * di;
    }
}

// ---------------- pass A: binned degree count, packed u16 (LDS atomics only) ----------------
__global__ __launch_bounds__(SCAN_TPB) void k_binA(const int* __restrict__ dst,
                                                   unsigned* __restrict__ partA,
                                                   int E, int chunkA) {
    __shared__ unsigned cnt[RANGE2 / 2];   // 64 KB, 2 nodes per word
    for (int i = threadIdx.x; i < RANGE2 / 2; i += SCAN_TPB) cnt[i] = 0;
    __syncthreads();

    const int r = blockIdx.x % NB2;
    const int lo = r << RB2;
    const int e0 = (blockIdx.x / NB2) * chunkA;
    const int e1 = min(E, e0 + chunkA);
    for (int e = e0 + (int)threadIdx.x * 4; e + 3 < e1; e += SCAN_TPB * 4) {
        int4 d4 = *(const int4*)(dst + e);
        unsigned v;
        v = (unsigned)(d4.x - lo); if (v < RANGE2) atomicAdd(&cnt[v >> 1], 1u << ((v & 1) << 4));
        v = (unsigned)(d4.y - lo); if (v < RANGE2) atomicAdd(&cnt[v >> 1], 1u << ((v & 1) << 4));
        v = (unsigned)(d4.z - lo); if (v < RANGE2) atomicAdd(&cnt[v >> 1], 1u << ((v & 1) << 4));
        v = (unsigned)(d4.w - lo); if (v < RANGE2) atomicAdd(&cnt[v >> 1], 1u << ((v & 1) << 4));
    }
    __syncthreads();

    unsigned* outp = partA + (size_t)blockIdx.x * (RANGE2 / 2);
    for (int i = threadIdx.x; i < RANGE2 / 2; i += SCAN_TPB) outp[i] = cnt[i];
}

// ---------------- pass C: binned value scatter (LDS float atomics only) ----------------
__global__ __launch_bounds__(SCAN_TPB) void k_binC(const int* __restrict__ eidx,
                                                   const float* __restrict__ zs,
                                                   float* __restrict__ partf,
                                                   int E, int chunk) {
    __shared__ float acc[RANGE];
    for (int i = threadIdx.x; i < RANGE; i += SCAN_TPB) acc[i] = 0.0f;
    __syncthreads();

    const int r = blockIdx.x % NB;
    const int lo = r << RANGE_BITS;
    const int e0 = (blockIdx.x / NB) * chunk;
    const int e1 = min(E, e0 + chunk);
    for (int e = e0 + (int)threadIdx.x * 4; e + 3 < e1; e += SCAN_TPB * 4) {
        int4 s4 = *(const int4*)(eidx + e);        // src
        int4 d4 = *(const int4*)(eidx + E + e);    // dst
        unsigned v;
        v = (unsigned)(d4.x - lo); if (v < RANGE) atomicAdd(&acc[v], zs[s4.x]);
        v = (unsigned)(d4.y - lo); if (v < RANGE) atomicAdd(&acc[v], zs[s4.y]);
        v = (unsigned)(d4.z - lo); if (v < RANGE) atomicAdd(&acc[v], zs[s4.z]);
        v = (unsigned)(d4.w - lo); if (v < RANGE) atomicAdd(&acc[v], zs[s4.w]);
    }
    __syncthreads();

    float* outp = partf + (size_t)blockIdx.x * RANGE;
    for (int i = threadIdx.x; i < RANGE; i += SCAN_TPB) outp[i] = acc[i];
}

// ------- final: out = dinv * (sum partials + zs[self]) + (b_g.W_out + b_out) -------
__global__ __launch_bounds__(256) void k_redFinal(const float* __restrict__ partf,
                                                  const float* __restrict__ dinv,
                                                  const float* __restrict__ zs,
                                                  const float* __restrict__ b_g,
                                                  const float* __restrict__ W_out,
                                                  const float* __restrict__ b_out,
                                                  float* __restrict__ out, int N) {
    const int lane = threadIdx.x & 63;
    float c = b_g[lane] * W_out[lane];
#pragma unroll
    for (int off = 32; off > 0; off >>= 1)
        c += __shfl_xor(c, off, 64);
    c += b_out[0];

    int i = blockIdx.x * blockDim.x + threadIdx.x;
    if (i >= N) return;
    const int r = i >> RANGE_BITS, idx = i & (RANGE - 1);
    float a = zs[i];   // self-loop
#pragma unroll 4
    for (int m = 0; m < MCH; ++m)
        a += partf[((size_t)m * NB + r) * RANGE + idx];
    out[i] = fmaf(dinv[i], a, c);
}

// ---------------- launch ----------------

extern "C" void kernel_launch(void* const* d_in, const int* in_sizes, int n_in,
                              void* d_out, int out_size, void* d_ws, size_t ws_size,
                              hipStream_t stream) {
    const float* x     = (const float*)d_in[0];
    const int*   eidx  = (const int*)d_in[1];
    const float* W_in  = (const float*)d_in[2];
    const float* b_in  = (const float*)d_in[3];
    const float* W_g   = (const float*)d_in[4];
    const float* b_g   = (const float*)d_in[5];
    const float* W_out = (const float*)d_in[6];
    const float* b_out = (const float*)d_in[7];
    float* out = (float*)d_out;

    const int N = in_sizes[0] / IN_DIM;   // 100000
    const int E = in_sizes[1] / 2;        // 1600000

    // chunks: multiples of 4
    const int chunk  = (((E + MCH  - 1) / MCH ) + 3) & ~3;
    const int chunkA = (((E + MCH2 - 1) / MCH2) + 3) & ~3;

    // ws layout: region0 = max(partf 16.5MB, partA 16.8MB) | dinv[N] | zs[N]
    const size_t partElems0 = (size_t)NB * MCH * RANGE;              // binC floats
    const size_t partElemsA = (size_t)NB2 * MCH2 * (RANGE2 / 2);     // binA u32 words
    const size_t partElems = partElems0 > partElemsA ? partElems0 : partElemsA;
    unsigned* partA = (unsigned*)d_ws;    // consumed by k_dense before binC overwrites
    float*    partf = (float*)d_ws;
    float*    dinv  = (float*)d_ws + partElems;
    float*    zs    = dinv + N;

    const int nG = (N + DNODES - 1) / DNODES;   // 1563 dense blocks
    k_binA<<<NB2 * MCH2, SCAN_TPB, 0, stream>>>(eidx + E, partA, E, chunkA);
    k_dense<<<nG, 256, 0, stream>>>(x, W_in, b_in, W_g, W_out, partA, dinv, zs, N);
    k_binC<<<NB * MCH, SCAN_TPB, 0, stream>>>(eidx, zs, partf, E, chunk);
    k_redFinal<<<(N + 255) / 256, 256, 0, stream>>>(partf, dinv, zs, b_g, W_out, b_out, out, N);
}